// Round 12
// baseline (155.504 us; speedup 1.0000x reference)
//
#include <hip/hip_runtime.h>
#include <math.h>

#define NB 8
#define NC 256
#define NL 4096
#define NK 65
#define NSL (NL / 16)   // 256 l-tiles per batch

typedef float vf4 __attribute__((ext_vector_type(4)));
typedef float vf2 __attribute__((ext_vector_type(2)));

// Per-block stat slots (sr, si, sq, pad) -- fully overwritten every launch.
__device__ float4 g_part[NB * NSL];

// b64-granular swizzled LDS slot: row (0..255) x complex position p (0..15).
// swz = p ^ (row&15) ^ ((row>>4)&15): conflict-free for (a) weight-write
// (own row, p sweep), (b) Phase A reads rows j+16k (swz = pos^j^k -> 16
// distinct slots per 16-lane group), (c) Phase B reads rows 16R+s
// (swz = pos^s^R -> 16 distinct slots per group). Max slot 4095 = 32 KB.
__device__ __forceinline__ int sidx(int row, int p) {
    return (row << 4) + (p ^ (row & 15) ^ ((row >> 4) & 15));
}

// ---------------------------------------------------------------------------
// Packed conv core: v_pk_fma_f32 with op_sel broadcast (R8-proven).
//   lo lane: sr += x * kre      hi lane: si += x * kim
// ---------------------------------------------------------------------------
#define PKFMA_EVEN(ACC, WP, K2)                                             \
    asm("v_pk_fma_f32 %0, %1, %2, %0 op_sel:[0,0,0] op_sel_hi:[0,1,1]"      \
        : "+v"(ACC) : "v"(WP), "v"(K2))
#define PKFMA_ODD(ACC, WP, K2)                                              \
    asm("v_pk_fma_f32 %0, %1, %2, %0 op_sel:[1,0,0] op_sel_hi:[1,1,1]"      \
        : "+v"(ACC) : "v"(WP), "v"(K2))

#define LOAD16P(W2, off)                                                    \
    {                                                                       \
        const int g0_ = l0 + (off);                                         \
        if (g0_ >= 0 && g0_ + 16 <= NL) {  /* block-uniform branch */       \
            _Pragma("unroll")                                               \
            for (int q = 0; q < 4; ++q) {                                   \
                const float4 v_ = *(const float4*)(xr + g0_ + 4 * q);       \
                vf2 a_; a_.x = v_.x; a_.y = v_.y; W2[2*q]   = a_;           \
                vf2 b_; b_.x = v_.z; b_.y = v_.w; W2[2*q+1] = b_;           \
            }                                                               \
        } else {                                                            \
            _Pragma("unroll")                                               \
            for (int q = 0; q < 8; ++q) {                                   \
                const int g_ = g0_ + 2 * q;                                 \
                vf2 a_;                                                     \
                a_.x = (g_     >= 0 && g_     < NL) ? xr[g_]     : 0.0f;    \
                a_.y = (g_ + 1 >= 0 && g_ + 1 < NL) ? xr[g_ + 1] : 0.0f;    \
                W2[q] = a_;                                                 \
            }                                                               \
        }                                                                   \
    }

#define CHUNK16PK(LoP, HiP, tb)                                             \
    {                                                                       \
        _Pragma("unroll")                                                   \
        for (int j2 = 0; j2 < 16; ++j2) {                                   \
            vf2 k2_; k2_.x = kre[(tb) + j2]; k2_.y = kim[(tb) + j2];        \
            _Pragma("unroll")                                               \
            for (int i = 0; i < 16; ++i) {                                  \
                const int w_ = i + j2;                                      \
                const int p_ = w_ >> 1;                                     \
                vf2 wp_ = (p_ < 8) ? LoP[p_] : HiP[p_ - 8];                 \
                if ((w_ & 1) == 0) { PKFMA_EVEN(s2[i], wp_, k2_); }         \
                else               { PKFMA_ODD (s2[i], wp_, k2_); }         \
            }                                                               \
        }                                                                   \
    }

__device__ __forceinline__ int digitrev_shift(int pp) {
    int k = ((pp & 3) << 6) | (((pp >> 2) & 3) << 4)
          | (((pp >> 4) & 3) << 2) | ((pp >> 6) & 3);
    return k ^ 128;  // fftshift
}

// In-place DIF radix-4 butterfly on complex float2 regs (identical math to
// the R11 staged version: b1 = (t1 - i t3) w1, b2 = (t0 - t2) w2,
// b3 = (t1 + i t3) w3).
#define BFLY(A0, A1, A2, A3, W1R, W1I, W2R, W2I, W3R, W3I)                  \
    {                                                                       \
        float t0r = A0.x + A2.x, t0i = A0.y + A2.y;                         \
        float t1r = A0.x - A2.x, t1i = A0.y - A2.y;                         \
        float t2r = A1.x + A3.x, t2i = A1.y + A3.y;                         \
        float t3r = A1.x - A3.x, t3i = A1.y - A3.y;                         \
        A0.x = t0r + t2r;       A0.y = t0i + t2i;                           \
        float b2r = t0r - t2r,  b2i = t0i - t2i;                            \
        float b1r = t1r + t3i,  b1i = t1i - t3r;                            \
        float b3r = t1r - t3i,  b3i = t1i + t3r;                            \
        A1.x = b1r*(W1R) - b1i*(W1I);  A1.y = b1r*(W1I) + b1i*(W1R);        \
        A2.x = b2r*(W2R) - b2i*(W2I);  A2.y = b2r*(W2I) + b2i*(W2R);        \
        A3.x = b3r*(W3R) - b3i*(W3I);  A3.y = b3r*(W3I) + b3i*(W3R);        \
    }

// ---------------------------------------------------------------------------
// Fused: conv (65 taps, 4-buffer prefetch, packed-f32 FMA) + pre-weight
// stats + weight (inv_std deferred) + 256-pt FFT over channels in TWO
// register phases (R12): Phase A = stages 0+1 in registers (thread owns
// rows j+16k at one l-position; stage0 e=j+16i<64 via tw64-shfl, stage1
// e=4j one twiddle), Phase B = stages 2+3 in registers (rows 16R+s;
// stage2 twiddles are compile-time constants, stage3 w=1) with the final
// digit-reversed store fused straight to global THROUGH L2. 3 barriers
// (was 5), 48 b64 LDS ops (was 64 b128 -- half the bytes), conflict-free
// swizzle. Butterfly math identical to R11 -> bit-identical numerics.
// LDS exactly 32 KB; launch_bounds(256,4) keeps the no-spill VGPR choice.
// ---------------------------------------------------------------------------
__global__ __launch_bounds__(256, 4) void fused_conv_fft_kernel(
    const float* __restrict__ x,
    const float* __restrict__ kre,
    const float* __restrict__ kim,
    const float* __restrict__ wmag,
    const float* __restrict__ wang,
    float* __restrict__ out,
    int out_size)
{
    __shared__ __align__(16) float2 lb2[NC * 16];   // exactly 32768 B

    const int t = threadIdx.x;              // channel
    const int b = blockIdx.x & 7;           // batch == XCD
    const int st = blockIdx.x >> 3;         // tile index within batch
    const int l0 = st << 4;                 // tile base
    const int lane = t & 63, wv = t >> 6;

    const float* xr = x + (size_t)b * NC * NL + (size_t)t * NL;  // own row
    const bool interleaved = (out_size >= 2 * NB * NC * NL);

    vf2 s2[16];                             // packed (sr, si) accumulators
    #pragma unroll
    for (int i = 0; i < 16; ++i) { s2[i].x = 0.0f; s2[i].y = 0.0f; }

    // ---- conv: 65 taps, 4-buffer prefetched sliding window, no barriers --
    vf2 W0[8], W1[8], W2[8], W3[8];
    LOAD16P(W0, -32);
    LOAD16P(W1, -16);
    LOAD16P(W2, 0);
    LOAD16P(W3, 16);
    CHUNK16PK(W0, W1, 0);    // taps  0..15
    LOAD16P(W0, 32);         // words [32,48) -> consumed by chunk 48 + tail
    CHUNK16PK(W1, W2, 16);   // taps 16..31
    CHUNK16PK(W2, W3, 32);   // taps 32..47
    CHUNK16PK(W3, W0, 48);   // taps 48..63
    {   // tail tap j = 64: words rel [32, 47] == W0 pairs 0..7
        vf2 k2_; k2_.x = kre[64]; k2_.y = kim[64];
        #pragma unroll
        for (int i = 0; i < 16; ++i) {
            vf2 wp_ = W0[i >> 1];
            if ((i & 1) == 0) { PKFMA_EVEN(s2[i], wp_, k2_); }
            else              { PKFMA_ODD (s2[i], wp_, k2_); }
        }
    }

    // ---- stats on y = (sr, -si), PRE-weight (un-normalized), packed ----
    vf2 tsum; tsum.x = 0.0f; tsum.y = 0.0f;
    vf2 tsq2; tsq2.x = 0.0f; tsq2.y = 0.0f;
    #pragma unroll
    for (int i = 0; i < 16; ++i) {
        tsum = tsum + s2[i];
        tsq2 = __builtin_elementwise_fma(s2[i], s2[i], tsq2);
    }
    float tsr = tsum.x, tsi = -tsum.y, tsq = tsq2.x + tsq2.y;

    // ---- weight & twiddle constants ----
    float sw, cw;
    sincosf(wang[t], &sw, &cw);
    const float wm = wmag[t];
    const float wgr =  wm * cw;             // weight WITHOUT inv_std
    const float wgi = -wm * sw;
    float tw64r, tw64i;                     // exp(-2*pi*i*lane/256)
    {
        float ang = (float)lane * 0.024543692606170260f;  // 2*pi/256
        float s, c;
        sincosf(ang, &s, &c);
        tw64r = c; tw64i = -s;
    }

    // ---- weight: y' = y * (wgr + i*wgi) -> own row, b64 swizzled ----
    #pragma unroll
    for (int p = 0; p < 16; ++p) {
        float srA = s2[p].x, siA = s2[p].y;
        float2 o;
        o.x = srA * wgr + siA * wgi;
        o.y = srA * wgi - siA * wgr;
        lb2[sidx(t, p)] = o;
    }
    __syncthreads();

    // ---- Phase A: FFT stages 0 + 1 in registers ----
    {
        const int j = t & 15, pos = t >> 4;
        float2 z[16];
        #pragma unroll
        for (int k = 0; k < 16; ++k) z[k] = lb2[sidx(j + 16*k, pos)];

        // stage 0 (q=64): butterfly i over z[i], z[i+4], z[i+8], z[i+12];
        // e = j + 16i <= 63
        #pragma unroll
        for (int i = 0; i < 4; ++i) {
            int e = j + 16*i;
            float w1r = __shfl(tw64r, e);
            float w1i = __shfl(tw64i, e);
            float w2r = fmaf(w1r, w1r, -(w1i*w1i));
            float w2i = 2.0f * w1r * w1i;
            float w3r = w2r*w1r - w2i*w1i;
            float w3i = w2r*w1i + w2i*w1r;
            BFLY(z[i], z[i+4], z[i+8], z[i+12], w1r,w1i, w2r,w2i, w3r,w3i);
        }
        // stage 1 (q=16): butterfly blk over z[4blk..4blk+3]; e = 4j for all
        {
            int e = 4*j;
            float w1r = __shfl(tw64r, e);
            float w1i = __shfl(tw64i, e);
            float w2r = fmaf(w1r, w1r, -(w1i*w1i));
            float w2i = 2.0f * w1r * w1i;
            float w3r = w2r*w1r - w2i*w1i;
            float w3i = w2r*w1i + w2i*w1r;
            #pragma unroll
            for (int blk = 0; blk < 4; ++blk) {
                BFLY(z[4*blk], z[4*blk+1], z[4*blk+2], z[4*blk+3],
                     w1r,w1i, w2r,w2i, w3r,w3i);
            }
        }
        #pragma unroll
        for (int k = 0; k < 16; ++k) lb2[sidx(j + 16*k, pos)] = z[k];
    }
    __syncthreads();

    // ---- Phase B: FFT stages 2 + 3 in registers + fused global store ----
    {
        const int R = t & 15, pos = t >> 4;
        float2 y[16];
        #pragma unroll
        for (int s = 0; s < 16; ++s) y[s] = lb2[sidx(16*R + s, pos)];

        // stage 2 (q=4): butterfly j2 over y[j2+4c]; e = 16*j2 -> constants
        const float c16r  =  0.92387953251128674f, c16i  = -0.38268343236508978f;
        const float c32r  =  0.70710678118654757f, c32i  = -0.70710678118654746f;
        const float c48r  =  0.38268343236508984f, c48i  = -0.92387953251128674f;
        const float c64r  =  0.0f,                 c64i  = -1.0f;
        const float c96r  = -0.70710678118654746f, c96i  = -0.70710678118654757f;
        const float c144r = -0.92387953251128674f, c144i =  0.38268343236508984f;
        BFLY(y[0], y[4], y[8],  y[12], 1.0f,0.0f, 1.0f,0.0f, 1.0f,0.0f);
        BFLY(y[1], y[5], y[9],  y[13], c16r,c16i, c32r,c32i, c48r,c48i);
        BFLY(y[2], y[6], y[10], y[14], c32r,c32i, c64r,c64i, c96r,c96i);
        BFLY(y[3], y[7], y[11], y[15], c48r,c48i, c96r,c96i, c144r,c144i);
        // stage 3 (q=1, w=1): butterfly d over y[4d..4d+3]
        #pragma unroll
        for (int d = 0; d < 4; ++d) {
            BFLY(y[4*d], y[4*d+1], y[4*d+2], y[4*d+3],
                 1.0f,0.0f, 1.0f,0.0f, 1.0f,0.0f);
        }

        // digit-reverse + fftshift + store THROUGH L2 (un-normalized)
        #pragma unroll
        for (int s = 0; s < 16; ++s) {
            int pp = 16*R + s;
            int cout = digitrev_shift(pp);
            if (interleaved) {
                size_t fi = 2 * ((size_t)(b * NC + cout) * NL + l0 + pos);
                if (fi + 2 <= (size_t)out_size) {
                    *(float2*)(out + fi) = y[s];
                }
            } else {
                size_t fi = (size_t)(b * NC + cout) * NL + l0 + pos;
                if (fi < (size_t)out_size) {
                    out[fi] = y[s].x;
                }
            }
        }
    }

    // ---- block stats -> dedicated slot (reduce via LDS alias) ----
    #pragma unroll
    for (int off = 32; off > 0; off >>= 1) {
        tsr += __shfl_down(tsr, off);
        tsi += __shfl_down(tsi, off);
        tsq += __shfl_down(tsq, off);
    }
    __syncthreads();                        // Phase B LDS reads complete
    float* redf = (float*)lb2;
    if (lane == 0) { redf[wv*3+0] = tsr; redf[wv*3+1] = tsi; redf[wv*3+2] = tsq; }
    __syncthreads();
    if (t == 0) {
        float a0 = 0.0f, a1 = 0.0f, a2 = 0.0f;
        #pragma unroll
        for (int i = 0; i < 4; ++i) { a0 += redf[i*3]; a1 += redf[i*3+1]; a2 += redf[i*3+2]; }
        g_part[b * NSL + st] = make_float4(a0, a1, a2, 0.0f);
    }
}

// ---------------------------------------------------------------------------
// Per-batch inv_std from g_part (each block redundantly reduces its own
// batch's 256 slots -- 4 KB, L2-hot) + contiguous scale of its out range,
// all THROUGH L2/L3. XCD-affine: block j -> batch j&7.
// ---------------------------------------------------------------------------
__global__ __launch_bounds__(256) void scale_out_kernel(
    float* __restrict__ out, int out_size)
{
    __shared__ float sred[13];
    const int t = threadIdx.x;
    const int j = blockIdx.x;               // 0..2047
    const int b = j & 7;                    // batch == XCD
    const int seg = j >> 3;                 // 256 segments per batch
    const int lane = t & 63, wv = t >> 6;

    // reduce batch b's 256 slots (thread t -> slot t)
    float4 p = g_part[b * NSL + t];
    float psr = p.x, psi = p.y, psq = p.z;
    #pragma unroll
    for (int off = 32; off > 0; off >>= 1) {
        psr += __shfl_down(psr, off);
        psi += __shfl_down(psi, off);
        psq += __shfl_down(psq, off);
    }
    if (lane == 0) { sred[wv*3+0] = psr; sred[wv*3+1] = psi; sred[wv*3+2] = psq; }
    __syncthreads();
    if (t == 0) {
        float a0 = 0.0f, a1 = 0.0f, a2 = 0.0f;
        #pragma unroll
        for (int i = 0; i < 4; ++i) { a0 += sred[i*3]; a1 += sred[i*3+1]; a2 += sred[i*3+2]; }
        const float n = (float)(NC * NL);
        float var = (a2 - (a0*a0 + a1*a1)/n) / (n - 1.0f);
        sred[12] = rsqrtf(var);
    }
    __syncthreads();
    const float inv = sred[12];

    const int fpbatch = out_size >> 3;      // floats per batch
    const int fpseg = fpbatch >> 8;         // floats per segment
    const int base = b * fpbatch + seg * fpseg;
    if ((fpseg & 3) == 0 && ((size_t)(out + base) & 15) == 0) {
        float4* o4 = (float4*)(out + base);
        const int n4 = fpseg >> 2;
        for (int i = t; i < n4; i += 256) {
            float4 v = o4[i];
            v.x *= inv; v.y *= inv; v.z *= inv; v.w *= inv;
            o4[i] = v;
        }
    } else {
        for (int i = t; i < fpseg; i += 256) out[base + i] *= inv;
    }
    // tail (out_size not divisible by 2048): belongs to the last batch,
    // and block j==2047 has b==7.
    if (j == 2047) {
        for (int i = ((out_size >> 11) << 11) + t; i < out_size; i += 256)
            out[i] *= inv;
    }
}

extern "C" void kernel_launch(void* const* d_in, const int* in_sizes, int n_in,
                              void* d_out, int out_size, void* d_ws, size_t ws_size,
                              hipStream_t stream)
{
    const float* x   = (const float*)d_in[0];
    const float* kre = (const float*)d_in[1];
    const float* kim = (const float*)d_in[2];
    const float* wm  = (const float*)d_in[3];
    const float* wa  = (const float*)d_in[4];
    float* out = (float*)d_out;
    (void)d_ws; (void)ws_size;

    fused_conv_fft_kernel<<<NB * NSL, 256, 0, stream>>>(x, kre, kim, wm, wa,
                                                        out, out_size);
    scale_out_kernel<<<2048, 256, 0, stream>>>(out, out_size);
}